// Round 1
// baseline (3886.643 us; speedup 1.0000x reference)
//
#include <hip/hip_runtime.h>
#include <math.h>

#define NE 160000
#define NN 10000
#define NP1 13
#define CG_TOTAL 573
#define G_TOTAL 145   // sum over paths of d1*d3
#define G_PAD 148

// path metadata (l1,l2,l3) in reference enumeration order
constexpr int c_l1[NP1]   = {0,0,0,1,1,1,1,1,2,2,2,2,2};
constexpr int c_l2[NP1]   = {0,1,2,0,1,1,2,3,0,1,2,2,3};
constexpr int c_l3[NP1]   = {0,1,2,1,0,2,1,2,2,1,0,2,1};
constexpr int c_cgoff[NP1]= {0,1,10,35,44,53,98,143,248,273,318,343,468};
constexpr int c_goff[NP1] = {0,1,4,9,18,21,36,45,60,85,100,105,130};
constexpr int c_gsz[NP1]  = {1,3,5,9,3,15,9,15,25,15,5,25,15}; // d1*d3
constexpr int YB[4] = {0,1,4,9};   // Y base per l2 in 16-float edge record
constexpr int KB[3] = {0,1,4};     // k-slot base per l3
constexpr int IB[3] = {0,1,4};     // i-slot base per l1

// ---------------- CG computation (device, double) ----------------
__device__ double dfact(int n){ double f=1.0; for(int i=2;i<=n;++i) f*=(double)i; return f; }

__device__ double cg_coef(int j1,int m1,int j2,int m2,int j3,int m3){
  if(m1+m2!=m3) return 0.0;
  double pref = sqrt((2.0*j3+1.0)*dfact(j3+j1-j2)*dfact(j3-j1+j2)*dfact(j1+j2-j3)/dfact(j1+j2+j3+1));
  pref *= sqrt(dfact(j3+m3)*dfact(j3-m3)*dfact(j1-m1)*dfact(j1+m1)*dfact(j2-m2)*dfact(j2+m2));
  double s=0.0;
  for(int k=0;k<=j1+j2-j3;++k){
    int d0=k, d1=j1+j2-j3-k, d2=j1-m1-k, d3=j2+m2-k, d4=j3-j2+m1+k, d5=j3-j1-m2+k;
    if(d1<0||d2<0||d3<0||d4<0||d5<0) continue;
    double denom = dfact(d0)*dfact(d1)*dfact(d2)*dfact(d3)*dfact(d4)*dfact(d5);
    s += ((k&1)? -1.0:1.0)/denom;
  }
  return pref*s;
}

__device__ void real_basis(int l, double Ar[7][7], double Ai[7][7]){
  for(int i=0;i<7;i++)for(int j=0;j<7;j++){Ar[i][j]=0.0;Ai[i][j]=0.0;}
  const double is2 = 0.70710678118654752440;
  for(int mp=-l;mp<=l;++mp){
    if(mp>0){ Ar[l+mp][l+mp] = ((mp&1)? -1.0:1.0)*is2; Ar[l+mp][l-mp] = is2; }
    else if(mp==0){ Ar[l][l]=1.0; }
    else { int m=-mp; Ai[l+mp][l-m] = is2; Ai[l+mp][l+m] = -(((m&1)?-1.0:1.0))*is2; }
  }
}

__global__ void k_cg(float* __restrict__ cg_out){
  int p = threadIdx.x;
  if(p>=NP1) return;
  int l1=c_l1[p], l2=c_l2[p], l3=c_l3[p];
  int d1=2*l1+1, d2=2*l2+1, d3=2*l3+1;
  double Cc[5][7][5];
  for(int a=0;a<5;a++)for(int b=0;b<7;b++)for(int c=0;c<5;c++) Cc[a][b][c]=0.0;
  for(int a=-l1;a<=l1;a++)for(int b=-l2;b<=l2;b++){
    int c=a+b;
    if(c>=-l3 && c<=l3) Cc[l1+a][l2+b][l3+c]=cg_coef(l1,a,l2,b,l3,c);
  }
  double A1r[7][7],A1i[7][7],A2r[7][7],A2i[7][7],A3r[7][7],A3i[7][7];
  real_basis(l1,A1r,A1i); real_basis(l2,A2r,A2i); real_basis(l3,A3r,A3i);
  double Crr[5][7][5], Cri[5][7][5];
  double sr=0.0, si=0.0;
  for(int i=0;i<d1;i++)for(int j=0;j<d2;j++)for(int k=0;k<d3;k++){
    double accr=0.0, acci=0.0;
    for(int a=0;a<d1;a++){
      double a1r=A1r[i][a], a1i=A1i[i][a];
      if(a1r==0.0 && a1i==0.0) continue;
      for(int b=0;b<d2;b++){
        double a2r=A2r[j][b], a2i=A2i[j][b];
        if(a2r==0.0 && a2i==0.0) continue;
        double p12r=a1r*a2r-a1i*a2i, p12i=a1r*a2i+a1i*a2r;
        for(int c=0;c<d3;c++){
          double cc=Cc[a][b][c]; if(cc==0.0) continue;
          double a3r=A3r[k][c], a3i=-A3i[k][c]; // conj
          accr += (p12r*a3r - p12i*a3i)*cc;
          acci += (p12r*a3i + p12i*a3r)*cc;
        }
      }
    }
    Crr[i][j][k]=accr; Cri[i][j][k]=acci;
    sr+=fabs(accr); si+=fabs(acci);
  }
  bool useR = (sr>=si);
  double nrm=0.0;
  for(int i=0;i<d1;i++)for(int j=0;j<d2;j++)for(int k=0;k<d3;k++){
    double v = useR? Crr[i][j][k] : Cri[i][j][k];
    nrm += v*v;
  }
  nrm = sqrt(nrm); if(nrm<1e-12) nrm=1e-12;
  for(int i=0;i<d1;i++)for(int j=0;j<d2;j++)for(int k=0;k<d3;k++){
    double v = useR? Crr[i][j][k] : Cri[i][j][k];
    cg_out[c_cgoff[p] + (i*d2+j)*d3 + k] = (float)(v/nrm);
  }
}

// ---------------- edge geometry + radial basis ----------------
__global__ void k_edge(const float* __restrict__ pos, const int* __restrict__ snd,
                       const int* __restrict__ rcv, float* __restrict__ ys, float* __restrict__ rad){
  int e = blockIdx.x*blockDim.x + threadIdx.x;
  if(e>=NE) return;
  int s=snd[e], r=rcv[e];
  float dx=pos[r*3+0]-pos[s*3+0];
  float dy=pos[r*3+1]-pos[s*3+1];
  float dz=pos[r*3+2]-pos[s*3+2];
  float rr = sqrtf(dx*dx+dy*dy+dz*dz + 1e-12f);
  float x=dx/rr, y=dy/rr, z=dz/rr;
  float* Y=&ys[e*16];
  Y[0]=1.f;
  const float s3=1.7320508075688772f;
  Y[1]=s3*y; Y[2]=s3*z; Y[3]=s3*x;
  const float s15=3.872983346207417f;
  const float s5h=1.118033988749895f;   // sqrt(5)/2
  Y[4]=s15*x*y; Y[5]=s15*y*z; Y[6]=s5h*(3.f*z*z-1.f); Y[7]=s15*x*z; Y[8]=0.5f*s15*(x*x-y*y);
  const float s35_8=2.0916500663351889f;  // sqrt(35/8)
  const float s105=10.246950765959598f;
  const float s21_8=1.6201851746019651f;  // sqrt(21/8)
  const float s7h=1.3228756555322954f;    // sqrt(7)/2
  Y[9]=s35_8*y*(3.f*x*x-y*y);
  Y[10]=s105*x*y*z;
  Y[11]=s21_8*y*(5.f*z*z-1.f);
  Y[12]=s7h*z*(5.f*z*z-3.f);
  Y[13]=s21_8*x*(5.f*z*z-1.f);
  Y[14]=0.5f*s105*z*(x*x-y*y);
  Y[15]=s35_8*x*(x*x-3.f*y*y);
  // radial: bessel * soft envelope
  float t = 2.f*(1.f - rr*0.2f);
  float env = (t>0.f)? 1.9784655248401538f*expf(-1.f/t) : 0.f;
  float rs = fmaxf(rr,1e-6f);
  const float sq25 = 0.6324555320336759f; // sqrt(2/5)
  float pre = sq25/rs * env;
  const float pi5 = 0.6283185307179586f;  // pi/5
  #pragma unroll
  for(int b=0;b<8;b++){
    rad[e*8+b] = pre * sinf((float)(b+1)*pi5*rs);
  }
}

__device__ inline float silu(float a){ return a/(1.f+expf(-a)); }

// ---------------- layer 0 messages (3 paths, l1=0) ----------------
__global__ __launch_bounds__(256) void k_msg0(const float* __restrict__ cg, const float* __restrict__ ys,
    const float* __restrict__ rad, const int* __restrict__ snd, const int* __restrict__ rcv,
    const int* __restrict__ spec, const float* __restrict__ wemb,
    const float* __restrict__ W1, const float* __restrict__ W2, float* __restrict__ acc){
  const int lane = threadIdx.x & 63;
  const int wid  = threadIdx.x >> 6;
  for(int base = blockIdx.x*16; base < NE; base += gridDim.x*16){
    int e0 = base + wid*4;
    float hval[4]; int sv[4], rv[4];
    float w[3][4];
    #pragma unroll
    for(int e=0;e<4;e++){
      int eid=e0+e;
      sv[e]=snd[eid]; rv[e]=rcv[eid];
      const float* rd=&rad[eid*8];
      float a=0.f;
      #pragma unroll
      for(int b=0;b<8;b++) a += rd[b]*W1[b*64+lane];
      hval[e]=silu(a);
      w[0][e]=0.f; w[1][e]=0.f; w[2][e]=0.f;
    }
    for(int m=0;m<64;m++){
      float w2v0=W2[m*192+lane], w2v1=W2[m*192+64+lane], w2v2=W2[m*192+128+lane];
      #pragma unroll
      for(int e=0;e<4;e++){
        float hm=__shfl(hval[e],m,64);
        w[0][e]+=hm*w2v0; w[1][e]+=hm*w2v1; w[2][e]+=hm*w2v2;
      }
    }
    #pragma unroll
    for(int e=0;e<4;e++){
      int eid=e0+e;
      float hs=wemb[spec[sv[e]]*64+lane];
      const float* Y=&ys[eid*16];
      float mk[9];
      mk[0] = w[0][e]*hs*cg[0];
      #pragma unroll
      for(int k=0;k<3;k++){
        float g=0.f;
        #pragma unroll
        for(int j=0;j<3;j++) g += Y[1+j]*cg[1+j*3+k];
        mk[1+k]=w[1][e]*hs*g;
      }
      #pragma unroll
      for(int k=0;k<5;k++){
        float g=0.f;
        #pragma unroll
        for(int j=0;j<5;j++) g += Y[4+j]*cg[10+j*5+k];
        mk[4+k]=w[2][e]*hs*g;
      }
      float* ap=&acc[(size_t)rv[e]*576 + lane];
      #pragma unroll
      for(int kk=0;kk<9;kk++) unsafeAtomicAdd(ap+kk*64, mk[kk]);
    }
  }
}

// ---------------- layer 1 messages (13 paths) ----------------
__global__ __launch_bounds__(256) void k_msg1(const float* __restrict__ cg, const float* __restrict__ ys,
    const float* __restrict__ rad, const int* __restrict__ snd, const int* __restrict__ rcv,
    const float* __restrict__ h0, const float* __restrict__ W1, const float* __restrict__ W2,
    float* __restrict__ acc){
  __shared__ float lds_cg[CG_TOTAL];
  __shared__ float lds_G[16*G_PAD];
  const int lane = threadIdx.x & 63;
  const int wid  = threadIdx.x >> 6;
  for(int t=threadIdx.x;t<CG_TOTAL;t+=256) lds_cg[t]=cg[t];
  __syncthreads();
  for(int base = blockIdx.x*16; base < NE; base += gridDim.x*16){
    int e0 = base + wid*4;
    int sv[4], rv[4]; float hval[4];
    #pragma unroll
    for(int e=0;e<4;e++){
      int eid=e0+e;
      sv[e]=snd[eid]; rv[e]=rcv[eid];
      const float* rd=&rad[eid*8];
      float a=0.f;
      #pragma unroll
      for(int b=0;b<8;b++) a += rd[b]*W1[b*64+lane];
      hval[e]=silu(a);
    }
    // phase B: cooperative G_p[i,k] = sum_j Y[l2][j]*CG[i,j,k] for this wave's 4 edges
    for(int t=0;t<10;t++){
      int g = lane + 64*t;
      if(g < 4*G_TOTAL){
        int e = g/G_TOTAL, r = g - G_TOTAL*e;
        int p=0, rr=r;
        while(rr >= c_gsz[p]){ rr -= c_gsz[p]; p++; }
        int l2=c_l2[p], l3=c_l3[p];
        int d3=2*l3+1, d2=2*l2+1;
        int i=rr/d3, k=rr-d3*i;
        const float* Y=&ys[(e0+e)*16 + YB[l2]];
        float gv=0.f;
        for(int j=0;j<d2;j++) gv += Y[j]*lds_cg[c_cgoff[p] + (i*d2+j)*d3 + k];
        lds_G[(wid*4+e)*G_PAD + r]=gv;
      }
    }
    __syncthreads();
    // phase C: w[p][e] = sum_m hidden[e][m]*W2[m, p*64+lane]
    float w[13][4];
    #pragma unroll
    for(int p=0;p<13;p++){
      #pragma unroll
      for(int e=0;e<4;e++) w[p][e]=0.f;
    }
    for(int m=0;m<64;m++){
      float hm[4];
      #pragma unroll
      for(int e=0;e<4;e++) hm[e]=__shfl(hval[e],m,64);
      const float* w2r=&W2[m*832+lane];
      #pragma unroll
      for(int p=0;p<13;p++){
        float w2v=w2r[p*64];
        #pragma unroll
        for(int e=0;e<4;e++) w[p][e]+=hm[e]*w2v;
      }
    }
    // phase D: contraction + scatter
    #pragma unroll 1
    for(int e=0;e<4;e++){
      const float* hb=&h0[(size_t)sv[e]*576 + lane];
      float hsv[9];
      #pragma unroll
      for(int i=0;i<9;i++) hsv[i]=hb[i*64];
      float mk[9];
      #pragma unroll
      for(int kk=0;kk<9;kk++) mk[kk]=0.f;
      const float* G=&lds_G[(wid*4+e)*G_PAD];
      #pragma unroll
      for(int p=0;p<13;p++){
        const int l1=c_l1[p], l3=c_l3[p];
        const int d1=2*l1+1, d3=2*l3+1;
        const int ib=IB[l1], kb=KB[l3], go=c_goff[p];
        float wp=w[p][e];
        #pragma unroll
        for(int k=0;k<d3;k++){
          float tk=0.f;
          #pragma unroll
          for(int i=0;i<d1;i++) tk += hsv[ib+i]*G[go+i*d3+k];
          mk[kb+k] += wp*tk;
        }
      }
      float* ap=&acc[(size_t)rv[e]*576 + lane];
      #pragma unroll
      for(int kk=0;kk<9;kk++) unsafeAtomicAdd(ap+kk*64, mk[kk]);
    }
    __syncthreads();
  }
}

// ---------------- node update 0: mix0 -> h0, read0 -> out[0:576] ----------------
__global__ __launch_bounds__(64) void k_node0(const float* __restrict__ acc, const float* __restrict__ mix,
    const float* __restrict__ read, float* __restrict__ h0, float* __restrict__ out){
  __shared__ float nm[9][64];
  __shared__ float hl[9][64];
  int n=blockIdx.x, d=threadIdx.x;
  #pragma unroll
  for(int kk=0;kk<9;kk++) nm[kk][d]=acc[(size_t)n*576 + kk*64 + d]*(1.f/16.f);
  __syncthreads();
  float h[9];
  #pragma unroll
  for(int kk=0;kk<9;kk++) h[kk]=0.f;
  for(int c=0;c<64;c++){
    float m0=mix[c*64+d], m1=mix[4096+c*64+d], m2=mix[8192+c*64+d];
    h[0]+=nm[0][c]*m0;
    #pragma unroll
    for(int k=0;k<3;k++) h[1+k]+=nm[1+k][c]*m1;
    #pragma unroll
    for(int k=0;k<5;k++) h[4+k]+=nm[4+k][c]*m2;
  }
  #pragma unroll
  for(int kk=0;kk<9;kk++){ h0[(size_t)n*576 + kk*64 + d]=h[kk]; hl[kk][d]=h[kk]; }
  __syncthreads();
  float o[9];
  #pragma unroll
  for(int kk=0;kk<9;kk++) o[kk]=0.f;
  for(int c=0;c<64;c++){
    float r0=read[c*64+d], r1=read[4096+c*64+d], r2=read[8192+c*64+d];
    o[0]+=hl[0][c]*r0;
    #pragma unroll
    for(int k=0;k<3;k++) o[1+k]+=hl[1+k][c]*r1;
    #pragma unroll
    for(int k=0;k<5;k++) o[4+k]+=hl[4+k][c]*r2;
  }
  float* op=&out[(size_t)n*1152];
  op[d]=o[0];
  #pragma unroll
  for(int k=0;k<3;k++) op[64 + d*3+k]=o[1+k];
  #pragma unroll
  for(int k=0;k<5;k++) op[256 + d*5+k]=o[4+k];
}

// ---------------- node update 1: mix1 + skip1 -> h_new, read1 -> out[576:1152] ----------------
__global__ __launch_bounds__(64) void k_node1(const float* __restrict__ acc, const float* __restrict__ h0,
    const float* __restrict__ mix, const float* __restrict__ skip, const float* __restrict__ read,
    float* __restrict__ out){
  __shared__ float nm[9][64];
  __shared__ float h0l[9][64];
  __shared__ float hn[9][64];
  int n=blockIdx.x, d=threadIdx.x;
  #pragma unroll
  for(int kk=0;kk<9;kk++){
    nm[kk][d]=acc[(size_t)n*576 + kk*64 + d]*(1.f/16.f);
    h0l[kk][d]=h0[(size_t)n*576 + kk*64 + d];
  }
  __syncthreads();
  float h[9];
  #pragma unroll
  for(int kk=0;kk<9;kk++) h[kk]=0.f;
  for(int c=0;c<64;c++){
    float m0=mix[c*64+d], m1=mix[4096+c*64+d], m2=mix[8192+c*64+d];
    float s0=skip[c*64+d], s1=skip[4096+c*64+d], s2=skip[8192+c*64+d];
    h[0]+=nm[0][c]*m0 + h0l[0][c]*s0;
    #pragma unroll
    for(int k=0;k<3;k++) h[1+k]+=nm[1+k][c]*m1 + h0l[1+k][c]*s1;
    #pragma unroll
    for(int k=0;k<5;k++) h[4+k]+=nm[4+k][c]*m2 + h0l[4+k][c]*s2;
  }
  #pragma unroll
  for(int kk=0;kk<9;kk++) hn[kk][d]=h[kk];
  __syncthreads();
  float o[9];
  #pragma unroll
  for(int kk=0;kk<9;kk++) o[kk]=0.f;
  for(int c=0;c<64;c++){
    float r0=read[c*64+d], r1=read[4096+c*64+d], r2=read[8192+c*64+d];
    o[0]+=hn[0][c]*r0;
    #pragma unroll
    for(int k=0;k<3;k++) o[1+k]+=hn[1+k][c]*r1;
    #pragma unroll
    for(int k=0;k<5;k++) o[4+k]+=hn[4+k][c]*r2;
  }
  float* op=&out[(size_t)n*1152 + 576];
  op[d]=o[0];
  #pragma unroll
  for(int k=0;k<3;k++) op[64 + d*3+k]=o[1+k];
  #pragma unroll
  for(int k=0;k<5;k++) op[256 + d*5+k]=o[4+k];
}

extern "C" void kernel_launch(void* const* d_in, const int* in_sizes, int n_in,
                              void* d_out, int out_size, void* d_ws, size_t ws_size,
                              hipStream_t stream) {
  (void)in_sizes; (void)n_in; (void)out_size; (void)ws_size;
  const float* pos  =(const float*)d_in[0];
  const int*   spec =(const int*)  d_in[1];
  const int*   snd  =(const int*)  d_in[2];
  const int*   rcv  =(const int*)  d_in[3];
  const float* wemb =(const float*)d_in[4];
  const float* w1_0 =(const float*)d_in[5];
  const float* w2_0 =(const float*)d_in[6];
  const float* mix0 =(const float*)d_in[7];
  const float* read0=(const float*)d_in[8];
  const float* w1_1 =(const float*)d_in[9];
  const float* w2_1 =(const float*)d_in[10];
  const float* mix1 =(const float*)d_in[11];
  const float* skip1=(const float*)d_in[12];
  const float* read1=(const float*)d_in[13];
  float* out=(float*)d_out;
  float* ws =(float*)d_ws;

  float* cg   = ws;                       // 573 (pad to 1024)
  float* ys   = ws + 1024;                // NE*16
  float* rad  = ys + (size_t)NE*16;       // NE*8
  float* acc0 = rad + (size_t)NE*8;       // NN*576
  float* acc1 = acc0 + (size_t)NN*576;    // NN*576
  float* h0   = acc1 + (size_t)NN*576;    // NN*576

  k_cg<<<1,64,0,stream>>>(cg);
  k_edge<<<(NE+255)/256,256,0,stream>>>(pos,snd,rcv,ys,rad);
  hipMemsetAsync(acc0, 0, (size_t)NN*576*2*sizeof(float), stream);
  k_msg0<<<2048,256,0,stream>>>(cg,ys,rad,snd,rcv,spec,wemb,w1_0,w2_0,acc0);
  k_node0<<<NN,64,0,stream>>>(acc0,mix0,read0,h0,out);
  k_msg1<<<2048,256,0,stream>>>(cg,ys,rad,snd,rcv,h0,w1_1,w2_1,acc1);
  k_node1<<<NN,64,0,stream>>>(acc1,h0,mix1,skip1,read1,out);
}

// Round 2
// 1832.019 us; speedup vs baseline: 2.1215x; 2.1215x over previous
//
#include <hip/hip_runtime.h>
#include <math.h>

#define NE 160000
#define NN 10000
#define NP1 13
#define CG_TOTAL 573
#define G_TOTAL 145

typedef __attribute__((ext_vector_type(8))) short bf16x8;
typedef __attribute__((ext_vector_type(4))) float f32x4;

// path metadata (l1,l2,l3) in reference enumeration order
constexpr int c_l1[NP1]   = {0,0,0,1,1,1,1,1,2,2,2,2,2};
constexpr int c_l2[NP1]   = {0,1,2,0,1,1,2,3,0,1,2,2,3};
constexpr int c_l3[NP1]   = {0,1,2,1,0,2,1,2,2,1,0,2,1};
constexpr int c_cgoff[NP1]= {0,1,10,35,44,53,98,143,248,273,318,343,468};
constexpr int c_goff[NP1] = {0,1,4,9,18,21,36,45,60,85,100,105,130};
constexpr int YB[4] = {0,1,4,9};
constexpr int KB[3] = {0,1,4};
constexpr int IB[3] = {0,1,4};

// ---------------- static device scratch (avoids ws_size limits) ----------------
__device__ float g_cg[640];
__device__ int   g_dec[160];
__device__ float g_ys[(size_t)NE*16];
__device__ float g_rad[(size_t)NE*8];
__device__ unsigned short g_hb0[(size_t)NE*64];
__device__ unsigned short g_hb1[(size_t)NE*64];
__device__ unsigned short g_Bp0[12*2*64*8];
__device__ unsigned short g_Bp1[52*2*64*8];
__device__ unsigned short g_W0[(size_t)NE*192];
__device__ unsigned short g_W1[(size_t)NE*832];
__device__ float g_acc0[(size_t)NN*576];
__device__ float g_acc1[(size_t)NN*576];
__device__ float g_h0[(size_t)NN*576];
__device__ int g_cnt[NN];
__device__ int g_cur[NN];
__device__ int g_off[NN+1];
__device__ int g_perm[NE];

__device__ inline unsigned short f2bf(float f){
  unsigned u = __float_as_uint(f);
  unsigned r = (u + 0x7FFFu + ((u>>16)&1u)) >> 16;
  return (unsigned short)r;
}
__device__ inline float bf2f(unsigned short h){ return __uint_as_float(((unsigned)h)<<16); }
__device__ inline float silu(float a){ return a/(1.f+expf(-a)); }

// ---------------- CG computation (device, double) ----------------
__device__ double dfact(int n){ double f=1.0; for(int i=2;i<=n;++i) f*=(double)i; return f; }

__device__ double cg_coef(int j1,int m1,int j2,int m2,int j3,int m3){
  if(m1+m2!=m3) return 0.0;
  double pref = sqrt((2.0*j3+1.0)*dfact(j3+j1-j2)*dfact(j3-j1+j2)*dfact(j1+j2-j3)/dfact(j1+j2+j3+1));
  pref *= sqrt(dfact(j3+m3)*dfact(j3-m3)*dfact(j1-m1)*dfact(j1+m1)*dfact(j2-m2)*dfact(j2+m2));
  double s=0.0;
  for(int k=0;k<=j1+j2-j3;++k){
    int d0=k, d1=j1+j2-j3-k, d2=j1-m1-k, d3=j2+m2-k, d4=j3-j2+m1+k, d5=j3-j1-m2+k;
    if(d1<0||d2<0||d3<0||d4<0||d5<0) continue;
    double denom = dfact(d0)*dfact(d1)*dfact(d2)*dfact(d3)*dfact(d4)*dfact(d5);
    s += ((k&1)? -1.0:1.0)/denom;
  }
  return pref*s;
}

__device__ void real_basis(int l, double Ar[7][7], double Ai[7][7]){
  for(int i=0;i<7;i++)for(int j=0;j<7;j++){Ar[i][j]=0.0;Ai[i][j]=0.0;}
  const double is2 = 0.70710678118654752440;
  for(int mp=-l;mp<=l;++mp){
    if(mp>0){ Ar[l+mp][l+mp] = ((mp&1)? -1.0:1.0)*is2; Ar[l+mp][l-mp] = is2; }
    else if(mp==0){ Ar[l][l]=1.0; }
    else { int m=-mp; Ai[l+mp][l-m] = is2; Ai[l+mp][l+m] = -(((m&1)?-1.0:1.0))*is2; }
  }
}

__global__ void k_cg(){
  int p = threadIdx.x;
  if(p==0){
    int r=0;
    for(int q=0;q<NP1;q++){
      int l1=c_l1[q], l2=c_l2[q], l3=c_l3[q];
      int d1=2*l1+1, d2=2*l2+1, d3=2*l3+1;
      for(int i=0;i<d1;i++)for(int k=0;k<d3;k++){
        int cgs = c_cgoff[q] + i*d2*d3 + k;
        g_dec[r++] = cgs | (YB[l2]<<10) | (d2<<14) | (d3<<17);
      }
    }
  }
  if(p>=NP1) return;
  int l1=c_l1[p], l2=c_l2[p], l3=c_l3[p];
  int d1=2*l1+1, d2=2*l2+1, d3=2*l3+1;
  double Cc[5][7][5];
  for(int a=0;a<5;a++)for(int b=0;b<7;b++)for(int c=0;c<5;c++) Cc[a][b][c]=0.0;
  for(int a=-l1;a<=l1;a++)for(int b=-l2;b<=l2;b++){
    int c=a+b;
    if(c>=-l3 && c<=l3) Cc[l1+a][l2+b][l3+c]=cg_coef(l1,a,l2,b,l3,c);
  }
  double A1r[7][7],A1i[7][7],A2r[7][7],A2i[7][7],A3r[7][7],A3i[7][7];
  real_basis(l1,A1r,A1i); real_basis(l2,A2r,A2i); real_basis(l3,A3r,A3i);
  double Crr[5][7][5], Cri[5][7][5];
  double sr=0.0, si=0.0;
  for(int i=0;i<d1;i++)for(int j=0;j<d2;j++)for(int k=0;k<d3;k++){
    double accr=0.0, acci=0.0;
    for(int a=0;a<d1;a++){
      double a1r=A1r[i][a], a1i=A1i[i][a];
      if(a1r==0.0 && a1i==0.0) continue;
      for(int b=0;b<d2;b++){
        double a2r=A2r[j][b], a2i=A2i[j][b];
        if(a2r==0.0 && a2i==0.0) continue;
        double p12r=a1r*a2r-a1i*a2i, p12i=a1r*a2i+a1i*a2r;
        for(int c=0;c<d3;c++){
          double cc=Cc[a][b][c]; if(cc==0.0) continue;
          double a3r=A3r[k][c], a3i=-A3i[k][c];
          accr += (p12r*a3r - p12i*a3i)*cc;
          acci += (p12r*a3i + p12i*a3r)*cc;
        }
      }
    }
    Crr[i][j][k]=accr; Cri[i][j][k]=acci;
    sr+=fabs(accr); si+=fabs(acci);
  }
  bool useR = (sr>=si);
  double nrm=0.0;
  for(int i=0;i<d1;i++)for(int j=0;j<d2;j++)for(int k=0;k<d3;k++){
    double v = useR? Crr[i][j][k] : Cri[i][j][k];
    nrm += v*v;
  }
  nrm = sqrt(nrm); if(nrm<1e-12) nrm=1e-12;
  for(int i=0;i<d1;i++)for(int j=0;j<d2;j++)for(int k=0;k<d3;k++){
    double v = useR? Crr[i][j][k] : Cri[i][j][k];
    g_cg[c_cgoff[p] + (i*d2+j)*d3 + k] = (float)(v/nrm);
  }
}

// ---------------- misc small kernels ----------------
__global__ void k_zero(){
  int i = blockIdx.x*256 + threadIdx.x;
  if(i<NN){ g_cnt[i]=0; g_cur[i]=0; }
  else if(i<2*NN){ }
}

__global__ void k_hist(const int* __restrict__ rcv){
  int e = blockIdx.x*256 + threadIdx.x;
  if(e<NE) atomicAdd(&g_cnt[rcv[e]], 1);
}

__global__ void k_scan(){
  __shared__ int lds[1024];
  int t = threadIdx.x;
  int base = t*10;
  int s = 0;
  for(int i=0;i<10;i++){ int idx=base+i; if(idx<NN) s += g_cnt[idx]; }
  lds[t]=s; __syncthreads();
  for(int o=1;o<1024;o<<=1){
    int v = (t>=o)? lds[t-o] : 0;
    __syncthreads();
    lds[t]+=v;
    __syncthreads();
  }
  int run = lds[t]-s;
  for(int i=0;i<10;i++){ int idx=base+i; if(idx<NN){ g_off[idx]=run; run+=g_cnt[idx]; } }
  if(t==0) g_off[NN]=NE;
}

__global__ void k_scatter(const int* __restrict__ rcv){
  int e = blockIdx.x*256 + threadIdx.x;
  if(e<NE){
    int r = rcv[e];
    int p = atomicAdd(&g_cur[r],1);
    g_perm[g_off[r]+p] = e;
  }
}

// ---------------- edge geometry + radial basis ----------------
__global__ void k_edge(const float* __restrict__ pos, const int* __restrict__ snd,
                       const int* __restrict__ rcv){
  int e = blockIdx.x*blockDim.x + threadIdx.x;
  if(e>=NE) return;
  int s=snd[e], r=rcv[e];
  float dx=pos[r*3+0]-pos[s*3+0];
  float dy=pos[r*3+1]-pos[s*3+1];
  float dz=pos[r*3+2]-pos[s*3+2];
  float rr = sqrtf(dx*dx+dy*dy+dz*dz + 1e-12f);
  float x=dx/rr, y=dy/rr, z=dz/rr;
  float* Y=&g_ys[(size_t)e*16];
  Y[0]=1.f;
  const float s3=1.7320508075688772f;
  Y[1]=s3*y; Y[2]=s3*z; Y[3]=s3*x;
  const float s15=3.872983346207417f;
  const float s5h=1.118033988749895f;
  Y[4]=s15*x*y; Y[5]=s15*y*z; Y[6]=s5h*(3.f*z*z-1.f); Y[7]=s15*x*z; Y[8]=0.5f*s15*(x*x-y*y);
  const float s35_8=2.0916500663351889f;
  const float s105=10.246950765959598f;
  const float s21_8=1.6201851746019651f;
  const float s7h=1.3228756555322954f;
  Y[9]=s35_8*y*(3.f*x*x-y*y);
  Y[10]=s105*x*y*z;
  Y[11]=s21_8*y*(5.f*z*z-1.f);
  Y[12]=s7h*z*(5.f*z*z-3.f);
  Y[13]=s21_8*x*(5.f*z*z-1.f);
  Y[14]=0.5f*s105*z*(x*x-y*y);
  Y[15]=s35_8*x*(x*x-3.f*y*y);
  float t = 2.f*(1.f - rr*0.2f);
  float env = (t>0.f)? 1.9784655248401538f*expf(-1.f/t) : 0.f;
  float rs = fmaxf(rr,1e-6f);
  const float sq25 = 0.6324555320336759f;
  float pre = sq25/rs * env;
  const float pi5 = 0.6283185307179586f;
  #pragma unroll
  for(int b=0;b<8;b++){
    g_rad[(size_t)e*8+b] = pre * sinf((float)(b+1)*pi5*rs);
  }
}

// ---------------- hidden = silu(rad@W1) for both layers, bf16 ----------------
__global__ __launch_bounds__(256) void k_hidden(const float* __restrict__ W1a,
                                                const float* __restrict__ W1b){
  int idx = blockIdx.x*256 + threadIdx.x;   // idx = e*64 + c
  int c = idx & 63;
  const float* rd = &g_rad[(size_t)(idx>>6)*8];
  float a0=0.f, a1=0.f;
  #pragma unroll
  for(int b=0;b<8;b++){
    float rv = rd[b];
    a0 += rv*W1a[b*64+c];
    a1 += rv*W1b[b*64+c];
  }
  g_hb0[idx] = f2bf(silu(a0));
  g_hb1[idx] = f2bf(silu(a1));
}

// ---------------- W2 repack to B-frag layout (bf16) ----------------
template<int NCOLS>
__global__ void k_repack(const float* __restrict__ W2){
  constexpr int NCB = NCOLS/16;
  int t = blockIdx.x*256 + threadIdx.x;
  if(t >= NCB*128) return;
  int cb = t>>7, rest = t&127, ks = rest>>6, l = rest&63;
  int col = cb*16 + (l&15);
  unsigned short* dst = (NCOLS==832)? g_Bp1 : g_Bp0;
  #pragma unroll
  for(int j=0;j<8;j++){
    int k = ks*32 + ((l>>4)<<3) + j;
    dst[(size_t)t*8+j] = f2bf(W2[k*NCOLS + col]);
  }
}

// ---------------- W = hidden @ W2 via MFMA (bf16 in, bf16 out) ----------------
template<int NCOLS>
__global__ __launch_bounds__(256) void k_wgemm(){
  constexpr int NCB = NCOLS/16;
  const unsigned short* hb = (NCOLS==832)? g_hb1 : g_hb0;
  const unsigned short* Bp = (NCOLS==832)? g_Bp1 : g_Bp0;
  unsigned short* W = (NCOLS==832)? g_W1 : g_W0;
  const int lane = threadIdx.x & 63;
  const int wid  = threadIdx.x >> 6;
  const int e0 = blockIdx.x*128 + wid*32;   // 32 edges per wave
  const int rowl = lane & 15, kg = lane >> 4;
  bf16x8 a[2][2];
  #pragma unroll
  for(int mr=0;mr<2;mr++){
    #pragma unroll
    for(int ks=0;ks<2;ks++){
      a[mr][ks] = *reinterpret_cast<const bf16x8*>(&hb[(size_t)(e0+mr*16+rowl)*64 + ks*32 + kg*8]);
    }
  }
  for(int cb=0;cb<NCB;cb++){
    bf16x8 b0 = *reinterpret_cast<const bf16x8*>(&Bp[((size_t)(cb*2+0)*64+lane)*8]);
    bf16x8 b1 = *reinterpret_cast<const bf16x8*>(&Bp[((size_t)(cb*2+1)*64+lane)*8]);
    #pragma unroll
    for(int mr=0;mr<2;mr++){
      f32x4 acc = {0.f,0.f,0.f,0.f};
      acc = __builtin_amdgcn_mfma_f32_16x16x32_bf16(a[mr][0], b0, acc, 0,0,0);
      acc = __builtin_amdgcn_mfma_f32_16x16x32_bf16(a[mr][1], b1, acc, 0,0,0);
      #pragma unroll
      for(int r=0;r<4;r++){
        int row = kg*4 + r;
        W[(size_t)(e0+mr*16+row)*NCOLS + cb*16 + rowl] = f2bf(acc[r]);
      }
    }
  }
}

// ---------------- layer-0 gather (wave per node) ----------------
__global__ __launch_bounds__(256) void k_gather0(const int* __restrict__ snd,
    const int* __restrict__ spec, const float* __restrict__ wemb){
  __shared__ float lds_cg[36];
  __shared__ int lds_dec[9];
  __shared__ float Ylds[4][16];
  __shared__ float Glds[4][12];
  int tid=threadIdx.x;
  if(tid<36) lds_cg[tid]=g_cg[tid];
  if(tid>=64 && tid<73) lds_dec[tid-64]=g_dec[tid-64];
  __syncthreads();
  int lane=tid&63, wid=tid>>6;
  int n = blockIdx.x*4 + wid;
  int beg=g_off[n], end=g_off[n+1];
  float acc[9];
  #pragma unroll
  for(int kk=0;kk<9;kk++) acc[kk]=0.f;
  for(int j=beg;j<end;j++){
    int e = __builtin_amdgcn_readfirstlane(g_perm[j]);
    int s = __builtin_amdgcn_readfirstlane(snd[e]);
    if(lane<16) Ylds[wid][lane]=g_ys[(size_t)e*16+lane];
    const unsigned short* wp=&g_W0[(size_t)e*192 + lane];
    float wv0=bf2f(wp[0]), wv1=bf2f(wp[64]), wv2=bf2f(wp[128]);
    float hs=wemb[spec[s]*64+lane];
    asm volatile("s_waitcnt lgkmcnt(0)" ::: "memory");
    if(lane<9){
      int d=lds_dec[lane];
      int cgs=d&1023, yb=(d>>10)&15, d2=(d>>14)&7, d3=(d>>17)&7;
      float g=0.f;
      for(int jj=0;jj<d2;jj++) g+=Ylds[wid][yb+jj]*lds_cg[cgs+jj*d3];
      Glds[wid][lane]=g;
    }
    asm volatile("s_waitcnt lgkmcnt(0)" ::: "memory");
    float whs0=wv0*hs, whs1=wv1*hs, whs2=wv2*hs;
    acc[0]+=whs0*Glds[wid][0];
    #pragma unroll
    for(int k=0;k<3;k++) acc[1+k]+=whs1*Glds[wid][1+k];
    #pragma unroll
    for(int k=0;k<5;k++) acc[4+k]+=whs2*Glds[wid][4+k];
    asm volatile("s_waitcnt lgkmcnt(0)" ::: "memory");
  }
  #pragma unroll
  for(int kk=0;kk<9;kk++) g_acc0[(size_t)n*576+kk*64+lane]=acc[kk];
}

// ---------------- layer-1 gather (wave per node) ----------------
__global__ __launch_bounds__(256) void k_gather1(const int* __restrict__ snd){
  __shared__ float lds_cg[CG_TOTAL];
  __shared__ int lds_dec[G_TOTAL];
  __shared__ float Ylds[4][16];
  __shared__ float Glds[4][152];
  int tid=threadIdx.x;
  for(int t=tid;t<CG_TOTAL;t+=256) lds_cg[t]=g_cg[t];
  for(int t=tid;t<G_TOTAL;t+=256) lds_dec[t]=g_dec[t];
  __syncthreads();
  int lane=tid&63, wid=tid>>6;
  int n = blockIdx.x*4 + wid;
  int beg=g_off[n], end=g_off[n+1];
  float acc[9];
  #pragma unroll
  for(int kk=0;kk<9;kk++) acc[kk]=0.f;
  for(int j=beg;j<end;j++){
    int e = __builtin_amdgcn_readfirstlane(g_perm[j]);
    int s = __builtin_amdgcn_readfirstlane(snd[e]);
    if(lane<16) Ylds[wid][lane]=g_ys[(size_t)e*16+lane];
    float wv[13];
    const unsigned short* wp=&g_W1[(size_t)e*832 + lane];
    #pragma unroll
    for(int p=0;p<13;p++) wv[p]=bf2f(wp[p*64]);
    const float* hb=&g_h0[(size_t)s*576 + lane];
    float hsv[9];
    #pragma unroll
    for(int i=0;i<9;i++) hsv[i]=hb[i*64];
    asm volatile("s_waitcnt lgkmcnt(0)" ::: "memory");
    #pragma unroll
    for(int strip=0;strip<3;strip++){
      int r = lane + strip*64;
      if(r<G_TOTAL){
        int d=lds_dec[r];
        int cgs=d&1023, yb=(d>>10)&15, d2=(d>>14)&7, d3=(d>>17)&7;
        float g=0.f;
        for(int jj=0;jj<d2;jj++) g+=Ylds[wid][yb+jj]*lds_cg[cgs+jj*d3];
        Glds[wid][r]=g;
      }
    }
    asm volatile("s_waitcnt lgkmcnt(0)" ::: "memory");
    const float* G=&Glds[wid][0];
    #pragma unroll
    for(int p=0;p<13;p++){
      const int l1=c_l1[p], l3=c_l3[p];
      const int d1=2*l1+1, d3=2*l3+1;
      const int ib=IB[l1], kb=KB[l3], go=c_goff[p];
      float wpv=wv[p];
      #pragma unroll
      for(int k=0;k<d3;k++){
        float t=0.f;
        #pragma unroll
        for(int i=0;i<d1;i++) t += hsv[ib+i]*G[go+i*d3+k];
        acc[kb+k] += wpv*t;
      }
    }
    asm volatile("s_waitcnt lgkmcnt(0)" ::: "memory");
  }
  #pragma unroll
  for(int kk=0;kk<9;kk++) g_acc1[(size_t)n*576+kk*64+lane]=acc[kk];
}

// ---------------- node update 0 (wave per node) ----------------
__global__ __launch_bounds__(256) void k_node0(const float* __restrict__ mix,
    const float* __restrict__ read, float* __restrict__ out){
  __shared__ float nm[4][9][64];
  __shared__ float hl[4][9][64];
  int lane=threadIdx.x&63, wid=threadIdx.x>>6;
  int n=blockIdx.x*4+wid;
  #pragma unroll
  for(int kk=0;kk<9;kk++) nm[wid][kk][lane]=g_acc0[(size_t)n*576+kk*64+lane]*(1.f/16.f);
  asm volatile("s_waitcnt lgkmcnt(0)" ::: "memory");
  float h[9];
  #pragma unroll
  for(int kk=0;kk<9;kk++) h[kk]=0.f;
  for(int c=0;c<64;c++){
    float m0=mix[c*64+lane], m1=mix[4096+c*64+lane], m2=mix[8192+c*64+lane];
    h[0]+=nm[wid][0][c]*m0;
    #pragma unroll
    for(int k=0;k<3;k++) h[1+k]+=nm[wid][1+k][c]*m1;
    #pragma unroll
    for(int k=0;k<5;k++) h[4+k]+=nm[wid][4+k][c]*m2;
  }
  #pragma unroll
  for(int kk=0;kk<9;kk++){ g_h0[(size_t)n*576+kk*64+lane]=h[kk]; hl[wid][kk][lane]=h[kk]; }
  asm volatile("s_waitcnt lgkmcnt(0)" ::: "memory");
  float o[9];
  #pragma unroll
  for(int kk=0;kk<9;kk++) o[kk]=0.f;
  for(int c=0;c<64;c++){
    float r0=read[c*64+lane], r1=read[4096+c*64+lane], r2=read[8192+c*64+lane];
    o[0]+=hl[wid][0][c]*r0;
    #pragma unroll
    for(int k=0;k<3;k++) o[1+k]+=hl[wid][1+k][c]*r1;
    #pragma unroll
    for(int k=0;k<5;k++) o[4+k]+=hl[wid][4+k][c]*r2;
  }
  float* op=&out[(size_t)n*1152];
  op[lane]=o[0];
  #pragma unroll
  for(int k=0;k<3;k++) op[64 + lane*3+k]=o[1+k];
  #pragma unroll
  for(int k=0;k<5;k++) op[256 + lane*5+k]=o[4+k];
}

// ---------------- node update 1 (wave per node) ----------------
__global__ __launch_bounds__(256) void k_node1(const float* __restrict__ mix,
    const float* __restrict__ skip, const float* __restrict__ read, float* __restrict__ out){
  __shared__ float nm[4][9][64];
  __shared__ float h0l[4][9][64];
  __shared__ float hn[4][9][64];
  int lane=threadIdx.x&63, wid=threadIdx.x>>6;
  int n=blockIdx.x*4+wid;
  #pragma unroll
  for(int kk=0;kk<9;kk++){
    nm[wid][kk][lane]=g_acc1[(size_t)n*576+kk*64+lane]*(1.f/16.f);
    h0l[wid][kk][lane]=g_h0[(size_t)n*576+kk*64+lane];
  }
  asm volatile("s_waitcnt lgkmcnt(0)" ::: "memory");
  float h[9];
  #pragma unroll
  for(int kk=0;kk<9;kk++) h[kk]=0.f;
  for(int c=0;c<64;c++){
    float m0=mix[c*64+lane], m1=mix[4096+c*64+lane], m2=mix[8192+c*64+lane];
    float s0=skip[c*64+lane], s1=skip[4096+c*64+lane], s2=skip[8192+c*64+lane];
    h[0]+=nm[wid][0][c]*m0 + h0l[wid][0][c]*s0;
    #pragma unroll
    for(int k=0;k<3;k++) h[1+k]+=nm[wid][1+k][c]*m1 + h0l[wid][1+k][c]*s1;
    #pragma unroll
    for(int k=0;k<5;k++) h[4+k]+=nm[wid][4+k][c]*m2 + h0l[wid][4+k][c]*s2;
  }
  #pragma unroll
  for(int kk=0;kk<9;kk++) hn[wid][kk][lane]=h[kk];
  asm volatile("s_waitcnt lgkmcnt(0)" ::: "memory");
  float o[9];
  #pragma unroll
  for(int kk=0;kk<9;kk++) o[kk]=0.f;
  for(int c=0;c<64;c++){
    float r0=read[c*64+lane], r1=read[4096+c*64+lane], r2=read[8192+c*64+lane];
    o[0]+=hn[wid][0][c]*r0;
    #pragma unroll
    for(int k=0;k<3;k++) o[1+k]+=hn[wid][1+k][c]*r1;
    #pragma unroll
    for(int k=0;k<5;k++) o[4+k]+=hn[wid][4+k][c]*r2;
  }
  float* op=&out[(size_t)n*1152 + 576];
  op[lane]=o[0];
  #pragma unroll
  for(int k=0;k<3;k++) op[64 + lane*3+k]=o[1+k];
  #pragma unroll
  for(int k=0;k<5;k++) op[256 + lane*5+k]=o[4+k];
}

extern "C" void kernel_launch(void* const* d_in, const int* in_sizes, int n_in,
                              void* d_out, int out_size, void* d_ws, size_t ws_size,
                              hipStream_t stream) {
  (void)in_sizes; (void)n_in; (void)out_size; (void)d_ws; (void)ws_size;
  const float* pos  =(const float*)d_in[0];
  const int*   spec =(const int*)  d_in[1];
  const int*   snd  =(const int*)  d_in[2];
  const int*   rcv  =(const int*)  d_in[3];
  const float* wemb =(const float*)d_in[4];
  const float* w1_0 =(const float*)d_in[5];
  const float* w2_0 =(const float*)d_in[6];
  const float* mix0 =(const float*)d_in[7];
  const float* read0=(const float*)d_in[8];
  const float* w1_1 =(const float*)d_in[9];
  const float* w2_1 =(const float*)d_in[10];
  const float* mix1 =(const float*)d_in[11];
  const float* skip1=(const float*)d_in[12];
  const float* read1=(const float*)d_in[13];
  float* out=(float*)d_out;

  k_cg<<<1,64,0,stream>>>();
  k_zero<<<(2*NN+255)/256,256,0,stream>>>();
  k_edge<<<(NE+255)/256,256,0,stream>>>(pos,snd,rcv);
  k_hist<<<NE/256,256,0,stream>>>(rcv);
  k_scan<<<1,1024,0,stream>>>();
  k_scatter<<<NE/256,256,0,stream>>>(rcv);
  k_hidden<<<NE*64/256,256,0,stream>>>(w1_0,w1_1);
  k_repack<192><<<6,256,0,stream>>>(w2_0);
  k_repack<832><<<26,256,0,stream>>>(w2_1);
  k_wgemm<192><<<NE/128,256,0,stream>>>();
  k_wgemm<832><<<NE/128,256,0,stream>>>();
  k_gather0<<<NN/4,256,0,stream>>>(snd,spec,wemb);
  k_node0<<<NN/4,256,0,stream>>>(mix0,read0,out);
  k_gather1<<<NN/4,256,0,stream>>>(snd);
  k_node1<<<NN/4,256,0,stream>>>(mix1,skip1,read1,out);
}

// Round 3
// 670.257 us; speedup vs baseline: 5.7987x; 2.7333x over previous
//
#include <hip/hip_runtime.h>
#include <math.h>

#define NE 160000
#define NN 10000
#define NP1 13
#define CG_TOTAL 573
#define CC_TOTAL 171
#define G_TOTAL 145

typedef __attribute__((ext_vector_type(8))) short bf16x8;
typedef __attribute__((ext_vector_type(4))) float f32x4;

// path metadata (l1,l2,l3) in reference enumeration order
constexpr int c_l1[NP1]   = {0,0,0,1,1,1,1,1,2,2,2,2,2};
constexpr int c_l2[NP1]   = {0,1,2,0,1,1,2,3,0,1,2,2,3};
constexpr int c_l3[NP1]   = {0,1,2,1,0,2,1,2,2,1,0,2,1};
constexpr int c_cgoff[NP1+1]= {0,1,10,35,44,53,98,143,248,273,318,343,468,573};
constexpr int c_ccoff[NP1+1]= {0,1,4,9,12,21,30,45,66,71,86,111,136,171};
constexpr int c_goff[NP1] = {0,1,4,9,18,21,36,45,60,85,100,105,130};
constexpr int YB[4] = {0,1,4,9};
constexpr int KB[3] = {0,1,4};
constexpr int IB[3] = {0,1,4};

// ---------------- static device scratch ----------------
__device__ float g_cg[640];
__device__ int   g_dec[160];
__device__ float g_ys[(size_t)NE*16];
__device__ float g_rad[(size_t)NE*8];
__device__ unsigned short g_hb0[(size_t)NE*64];
__device__ unsigned short g_hb1[(size_t)NE*64];
__device__ unsigned short g_Bp0[12*2*64*8];
__device__ unsigned short g_Bp1[52*2*64*8];
__device__ unsigned short g_W0[(size_t)NE*192];
__device__ unsigned short g_W1[(size_t)NE*832];
__device__ float g_acc0[(size_t)NN*576];
__device__ float g_acc1[(size_t)NN*576];
__device__ float g_h0[(size_t)NN*576];
__device__ int g_cnt[NN];
__device__ int g_cur[NN];
__device__ int g_off[NN+1];
__device__ int g_perm[NE];

__device__ inline unsigned short f2bf(float f){
  unsigned u = __float_as_uint(f);
  unsigned r = (u + 0x7FFFu + ((u>>16)&1u)) >> 16;
  return (unsigned short)r;
}
__device__ inline float bf2f(unsigned short h){ return __uint_as_float(((unsigned)h)<<16); }
__device__ inline float silu(float a){ return a/(1.f+expf(-a)); }

// ---------------- CG computation (device, double, parallel) ----------------
__device__ double dfact(int n){ double f=1.0; for(int i=2;i<=n;++i) f*=(double)i; return f; }

__device__ double cg_coef(int j1,int m1,int j2,int m2,int j3,int m3){
  if(m1+m2!=m3) return 0.0;
  double pref = sqrt((2.0*j3+1.0)*dfact(j3+j1-j2)*dfact(j3-j1+j2)*dfact(j1+j2-j3)/dfact(j1+j2+j3+1));
  pref *= sqrt(dfact(j3+m3)*dfact(j3-m3)*dfact(j1-m1)*dfact(j1+m1)*dfact(j2-m2)*dfact(j2+m2));
  double s=0.0;
  for(int k=0;k<=j1+j2-j3;++k){
    int d0=k, d1=j1+j2-j3-k, d2=j1-m1-k, d3=j2+m2-k, d4=j3-j2+m1+k, d5=j3-j1-m2+k;
    if(d1<0||d2<0||d3<0||d4<0||d5<0) continue;
    double denom = dfact(d0)*dfact(d1)*dfact(d2)*dfact(d3)*dfact(d4)*dfact(d5);
    s += ((k&1)? -1.0:1.0)/denom;
  }
  return pref*s;
}

// real-basis matrix element A[l + mp][j] for degree l; i = row (0..2l), j = col (0..2l)
__device__ inline void rb_elem(int l, int i, int j, double& re, double& im){
  re=0.0; im=0.0;
  int mp = i - l;
  const double is2 = 0.70710678118654752440;
  if(mp>0){
    if(j==l+mp) re = ((mp&1)? -1.0:1.0)*is2;
    else if(j==l-mp) re = is2;
  } else if(mp==0){
    if(j==l) re = 1.0;
  } else {
    int m=-mp;
    if(j==l-m) im = is2;
    else if(j==l+m) im = -(((m&1)?-1.0:1.0))*is2;
  }
}

__global__ __launch_bounds__(1024) void k_cg(){
  __shared__ double s_cc[CC_TOTAL];
  __shared__ double s_crr[CG_TOTAL];
  __shared__ double s_cri[CG_TOTAL];
  __shared__ double s_inv[NP1];
  __shared__ int    s_useR[NP1];
  int tid = threadIdx.x;

  if(tid==0){
    int r=0;
    for(int q=0;q<NP1;q++){
      int l1=c_l1[q], l2=c_l2[q], l3=c_l3[q];
      int d1=2*l1+1, d2=2*l2+1, d3=2*l3+1;
      for(int i=0;i<d1;i++)for(int k=0;k<d3;k++){
        int cgs = c_cgoff[q] + i*d2*d3 + k;
        g_dec[r++] = cgs | (YB[l2]<<10) | (d2<<14) | (d3<<17);
      }
    }
  }

  // stage A: complex-basis CG entries Cc (one per (p, a_idx, b_idx))
  if(tid < CC_TOTAL){
    int p=0; while(tid >= c_ccoff[p+1]) p++;
    int r = tid - c_ccoff[p];
    int l1=c_l1[p], l2=c_l2[p], l3=c_l3[p];
    int d2=2*l2+1;
    int ai = r/d2, bi = r - ai*d2;
    int a = ai - l1, b = bi - l2, c = a + b;
    double v = 0.0;
    if(c >= -l3 && c <= l3) v = cg_coef(l1,a,l2,b,l3,c);
    s_cc[tid] = v;
  }
  __syncthreads();

  // stage B: real-basis transform, one thread per output entry (p,i,j,k)
  if(tid < CG_TOTAL){
    int p=0; while(tid >= c_cgoff[p+1]) p++;
    int r = tid - c_cgoff[p];
    int l1=c_l1[p], l2=c_l2[p], l3=c_l3[p];
    int d2=2*l2+1, d3=2*l3+1;
    int i = r/(d2*d3), rem = r - i*(d2*d3);
    int j = rem/d3, k = rem - j*d3;
    double accr=0.0, acci=0.0;
    int d1=2*l1+1;
    for(int ai=0; ai<d1; ai++){
      double a1r,a1i; rb_elem(l1,i,ai,a1r,a1i);
      if(a1r==0.0 && a1i==0.0) continue;
      for(int bi=0; bi<d2; bi++){
        double cc = s_cc[c_ccoff[p] + ai*d2 + bi];
        if(cc==0.0) continue;
        int ci = (ai - l1) + (bi - l2) + l3;   // c + l3
        if(ci < 0 || ci >= d3) continue;
        double a2r,a2i; rb_elem(l2,j,bi,a2r,a2i);
        if(a2r==0.0 && a2i==0.0) continue;
        double a3r,a3i; rb_elem(l3,k,ci,a3r,a3i);
        a3i = -a3i;  // conj
        double p12r = a1r*a2r - a1i*a2i;
        double p12i = a1r*a2i + a1i*a2r;
        accr += (p12r*a3r - p12i*a3i)*cc;
        acci += (p12r*a3i + p12i*a3r)*cc;
      }
    }
    s_crr[tid] = accr;
    s_cri[tid] = acci;
  }
  __syncthreads();

  // stage C: per-path select real/imag + normalize
  if(tid < NP1){
    int beg=c_cgoff[tid], end=c_cgoff[tid+1];
    double sr=0.0, si=0.0;
    for(int t=beg;t<end;t++){ sr += fabs(s_crr[t]); si += fabs(s_cri[t]); }
    int useR = (sr>=si);
    double nrm=0.0;
    for(int t=beg;t<end;t++){ double v = useR? s_crr[t] : s_cri[t]; nrm += v*v; }
    nrm = sqrt(nrm); if(nrm<1e-12) nrm=1e-12;
    s_useR[tid]=useR; s_inv[tid]=1.0/nrm;
  }
  __syncthreads();

  if(tid < CG_TOTAL){
    int p=0; while(tid >= c_cgoff[p+1]) p++;
    double v = s_useR[p]? s_crr[tid] : s_cri[tid];
    g_cg[tid] = (float)(v*s_inv[p]);
  }
}

// ---------------- misc small kernels ----------------
__global__ void k_zero(){
  int i = blockIdx.x*256 + threadIdx.x;
  if(i<NN){ g_cnt[i]=0; g_cur[i]=0; }
}

__global__ void k_hist(const int* __restrict__ rcv){
  int e = blockIdx.x*256 + threadIdx.x;
  if(e<NE) atomicAdd(&g_cnt[rcv[e]], 1);
}

__global__ void k_scan(){
  __shared__ int lds[1024];
  int t = threadIdx.x;
  int base = t*10;
  int s = 0;
  for(int i=0;i<10;i++){ int idx=base+i; if(idx<NN) s += g_cnt[idx]; }
  lds[t]=s; __syncthreads();
  for(int o=1;o<1024;o<<=1){
    int v = (t>=o)? lds[t-o] : 0;
    __syncthreads();
    lds[t]+=v;
    __syncthreads();
  }
  int run = lds[t]-s;
  for(int i=0;i<10;i++){ int idx=base+i; if(idx<NN){ g_off[idx]=run; run+=g_cnt[idx]; } }
  if(t==0) g_off[NN]=NE;
}

__global__ void k_scatter(const int* __restrict__ rcv){
  int e = blockIdx.x*256 + threadIdx.x;
  if(e<NE){
    int r = rcv[e];
    int p = atomicAdd(&g_cur[r],1);
    g_perm[g_off[r]+p] = e;
  }
}

// ---------------- edge geometry + radial basis ----------------
__global__ void k_edge(const float* __restrict__ pos, const int* __restrict__ snd,
                       const int* __restrict__ rcv){
  int e = blockIdx.x*blockDim.x + threadIdx.x;
  if(e>=NE) return;
  int s=snd[e], r=rcv[e];
  float dx=pos[r*3+0]-pos[s*3+0];
  float dy=pos[r*3+1]-pos[s*3+1];
  float dz=pos[r*3+2]-pos[s*3+2];
  float rr = sqrtf(dx*dx+dy*dy+dz*dz + 1e-12f);
  float x=dx/rr, y=dy/rr, z=dz/rr;
  float* Y=&g_ys[(size_t)e*16];
  Y[0]=1.f;
  const float s3=1.7320508075688772f;
  Y[1]=s3*y; Y[2]=s3*z; Y[3]=s3*x;
  const float s15=3.872983346207417f;
  const float s5h=1.118033988749895f;
  Y[4]=s15*x*y; Y[5]=s15*y*z; Y[6]=s5h*(3.f*z*z-1.f); Y[7]=s15*x*z; Y[8]=0.5f*s15*(x*x-y*y);
  const float s35_8=2.0916500663351889f;
  const float s105=10.246950765959598f;
  const float s21_8=1.6201851746019651f;
  const float s7h=1.3228756555322954f;
  Y[9]=s35_8*y*(3.f*x*x-y*y);
  Y[10]=s105*x*y*z;
  Y[11]=s21_8*y*(5.f*z*z-1.f);
  Y[12]=s7h*z*(5.f*z*z-3.f);
  Y[13]=s21_8*x*(5.f*z*z-1.f);
  Y[14]=0.5f*s105*z*(x*x-y*y);
  Y[15]=s35_8*x*(x*x-3.f*y*y);
  float t = 2.f*(1.f - rr*0.2f);
  float env = (t>0.f)? 1.9784655248401538f*expf(-1.f/t) : 0.f;
  float rs = fmaxf(rr,1e-6f);
  const float sq25 = 0.6324555320336759f;
  float pre = sq25/rs * env;
  const float pi5 = 0.6283185307179586f;
  #pragma unroll
  for(int b=0;b<8;b++){
    g_rad[(size_t)e*8+b] = pre * sinf((float)(b+1)*pi5*rs);
  }
}

// ---------------- hidden = silu(rad@W1) for both layers, bf16 ----------------
__global__ __launch_bounds__(256) void k_hidden(const float* __restrict__ W1a,
                                                const float* __restrict__ W1b){
  int idx = blockIdx.x*256 + threadIdx.x;   // idx = e*64 + c
  int c = idx & 63;
  const float* rd = &g_rad[(size_t)(idx>>6)*8];
  float a0=0.f, a1=0.f;
  #pragma unroll
  for(int b=0;b<8;b++){
    float rv = rd[b];
    a0 += rv*W1a[b*64+c];
    a1 += rv*W1b[b*64+c];
  }
  g_hb0[idx] = f2bf(silu(a0));
  g_hb1[idx] = f2bf(silu(a1));
}

// ---------------- W2 repack to B-frag layout (bf16) ----------------
template<int NCOLS>
__global__ void k_repack(const float* __restrict__ W2){
  constexpr int NCB = NCOLS/16;
  int t = blockIdx.x*256 + threadIdx.x;
  if(t >= NCB*128) return;
  int cb = t>>7, rest = t&127, ks = rest>>6, l = rest&63;
  int col = cb*16 + (l&15);
  unsigned short* dst = (NCOLS==832)? g_Bp1 : g_Bp0;
  #pragma unroll
  for(int j=0;j<8;j++){
    int k = ks*32 + ((l>>4)<<3) + j;
    dst[(size_t)t*8+j] = f2bf(W2[k*NCOLS + col]);
  }
}

// ---------------- W = hidden @ W2 via MFMA (bf16 in, bf16 out) ----------------
template<int NCOLS>
__global__ __launch_bounds__(256) void k_wgemm(){
  constexpr int NCB = NCOLS/16;
  const unsigned short* hb = (NCOLS==832)? g_hb1 : g_hb0;
  const unsigned short* Bp = (NCOLS==832)? g_Bp1 : g_Bp0;
  unsigned short* W = (NCOLS==832)? g_W1 : g_W0;
  const int lane = threadIdx.x & 63;
  const int wid  = threadIdx.x >> 6;
  const int e0 = blockIdx.x*128 + wid*32;   // 32 edges per wave
  const int rowl = lane & 15, kg = lane >> 4;
  bf16x8 a[2][2];
  #pragma unroll
  for(int mr=0;mr<2;mr++){
    #pragma unroll
    for(int ks=0;ks<2;ks++){
      a[mr][ks] = *reinterpret_cast<const bf16x8*>(&hb[(size_t)(e0+mr*16+rowl)*64 + ks*32 + kg*8]);
    }
  }
  for(int cb=0;cb<NCB;cb++){
    bf16x8 b0 = *reinterpret_cast<const bf16x8*>(&Bp[((size_t)(cb*2+0)*64+lane)*8]);
    bf16x8 b1 = *reinterpret_cast<const bf16x8*>(&Bp[((size_t)(cb*2+1)*64+lane)*8]);
    #pragma unroll
    for(int mr=0;mr<2;mr++){
      f32x4 acc = {0.f,0.f,0.f,0.f};
      acc = __builtin_amdgcn_mfma_f32_16x16x32_bf16(a[mr][0], b0, acc, 0,0,0);
      acc = __builtin_amdgcn_mfma_f32_16x16x32_bf16(a[mr][1], b1, acc, 0,0,0);
      #pragma unroll
      for(int r=0;r<4;r++){
        int row = kg*4 + r;
        W[(size_t)(e0+mr*16+row)*NCOLS + cb*16 + rowl] = f2bf(acc[r]);
      }
    }
  }
}

// ---------------- layer-0 gather (wave per node) ----------------
__global__ __launch_bounds__(256) void k_gather0(const int* __restrict__ snd,
    const int* __restrict__ spec, const float* __restrict__ wemb){
  __shared__ float lds_cg[36];
  __shared__ int lds_dec[9];
  __shared__ float Ylds[4][16];
  __shared__ float Glds[4][12];
  int tid=threadIdx.x;
  if(tid<36) lds_cg[tid]=g_cg[tid];
  if(tid>=64 && tid<73) lds_dec[tid-64]=g_dec[tid-64];
  __syncthreads();
  int lane=tid&63, wid=tid>>6;
  int n = blockIdx.x*4 + wid;
  int beg=g_off[n], end=g_off[n+1];
  float acc[9];
  #pragma unroll
  for(int kk=0;kk<9;kk++) acc[kk]=0.f;
  for(int j=beg;j<end;j++){
    int e = __builtin_amdgcn_readfirstlane(g_perm[j]);
    int s = __builtin_amdgcn_readfirstlane(snd[e]);
    if(lane<16) Ylds[wid][lane]=g_ys[(size_t)e*16+lane];
    const unsigned short* wp=&g_W0[(size_t)e*192 + lane];
    float wv0=bf2f(wp[0]), wv1=bf2f(wp[64]), wv2=bf2f(wp[128]);
    float hs=wemb[spec[s]*64+lane];
    asm volatile("s_waitcnt lgkmcnt(0)" ::: "memory");
    if(lane<9){
      int d=lds_dec[lane];
      int cgs=d&1023, yb=(d>>10)&15, d2=(d>>14)&7, d3=(d>>17)&7;
      float g=0.f;
      for(int jj=0;jj<d2;jj++) g+=Ylds[wid][yb+jj]*lds_cg[cgs+jj*d3];
      Glds[wid][lane]=g;
    }
    asm volatile("s_waitcnt lgkmcnt(0)" ::: "memory");
    float whs0=wv0*hs, whs1=wv1*hs, whs2=wv2*hs;
    acc[0]+=whs0*Glds[wid][0];
    #pragma unroll
    for(int k=0;k<3;k++) acc[1+k]+=whs1*Glds[wid][1+k];
    #pragma unroll
    for(int k=0;k<5;k++) acc[4+k]+=whs2*Glds[wid][4+k];
    asm volatile("s_waitcnt lgkmcnt(0)" ::: "memory");
  }
  #pragma unroll
  for(int kk=0;kk<9;kk++) g_acc0[(size_t)n*576+kk*64+lane]=acc[kk];
}

// ---------------- layer-1 gather (wave per node) ----------------
__global__ __launch_bounds__(256) void k_gather1(const int* __restrict__ snd){
  __shared__ float lds_cg[CG_TOTAL];
  __shared__ int lds_dec[G_TOTAL];
  __shared__ float Ylds[4][16];
  __shared__ float Glds[4][152];
  int tid=threadIdx.x;
  for(int t=tid;t<CG_TOTAL;t+=256) lds_cg[t]=g_cg[t];
  for(int t=tid;t<G_TOTAL;t+=256) lds_dec[t]=g_dec[t];
  __syncthreads();
  int lane=tid&63, wid=tid>>6;
  int n = blockIdx.x*4 + wid;
  int beg=g_off[n], end=g_off[n+1];
  float acc[9];
  #pragma unroll
  for(int kk=0;kk<9;kk++) acc[kk]=0.f;
  for(int j=beg;j<end;j++){
    int e = __builtin_amdgcn_readfirstlane(g_perm[j]);
    int s = __builtin_amdgcn_readfirstlane(snd[e]);
    if(lane<16) Ylds[wid][lane]=g_ys[(size_t)e*16+lane];
    float wv[13];
    const unsigned short* wp=&g_W1[(size_t)e*832 + lane];
    #pragma unroll
    for(int p=0;p<13;p++) wv[p]=bf2f(wp[p*64]);
    const float* hb=&g_h0[(size_t)s*576 + lane];
    float hsv[9];
    #pragma unroll
    for(int i=0;i<9;i++) hsv[i]=hb[i*64];
    asm volatile("s_waitcnt lgkmcnt(0)" ::: "memory");
    #pragma unroll
    for(int strip=0;strip<3;strip++){
      int r = lane + strip*64;
      if(r<G_TOTAL){
        int d=lds_dec[r];
        int cgs=d&1023, yb=(d>>10)&15, d2=(d>>14)&7, d3=(d>>17)&7;
        float g=0.f;
        for(int jj=0;jj<d2;jj++) g+=Ylds[wid][yb+jj]*lds_cg[cgs+jj*d3];
        Glds[wid][r]=g;
      }
    }
    asm volatile("s_waitcnt lgkmcnt(0)" ::: "memory");
    const float* G=&Glds[wid][0];
    #pragma unroll
    for(int p=0;p<13;p++){
      const int l1=c_l1[p], l3=c_l3[p];
      const int d1=2*l1+1, d3=2*l3+1;
      const int ib=IB[l1], kb=KB[l3], go=c_goff[p];
      float wpv=wv[p];
      #pragma unroll
      for(int k=0;k<d3;k++){
        float t=0.f;
        #pragma unroll
        for(int i=0;i<d1;i++) t += hsv[ib+i]*G[go+i*d3+k];
        acc[kb+k] += wpv*t;
      }
    }
    asm volatile("s_waitcnt lgkmcnt(0)" ::: "memory");
  }
  #pragma unroll
  for(int kk=0;kk<9;kk++) g_acc1[(size_t)n*576+kk*64+lane]=acc[kk];
}

// ---------------- node update 0 (wave per node) ----------------
__global__ __launch_bounds__(256) void k_node0(const float* __restrict__ mix,
    const float* __restrict__ read, float* __restrict__ out){
  __shared__ float nm[4][9][64];
  __shared__ float hl[4][9][64];
  int lane=threadIdx.x&63, wid=threadIdx.x>>6;
  int n=blockIdx.x*4+wid;
  #pragma unroll
  for(int kk=0;kk<9;kk++) nm[wid][kk][lane]=g_acc0[(size_t)n*576+kk*64+lane]*(1.f/16.f);
  asm volatile("s_waitcnt lgkmcnt(0)" ::: "memory");
  float h[9];
  #pragma unroll
  for(int kk=0;kk<9;kk++) h[kk]=0.f;
  for(int c=0;c<64;c++){
    float m0=mix[c*64+lane], m1=mix[4096+c*64+lane], m2=mix[8192+c*64+lane];
    h[0]+=nm[wid][0][c]*m0;
    #pragma unroll
    for(int k=0;k<3;k++) h[1+k]+=nm[wid][1+k][c]*m1;
    #pragma unroll
    for(int k=0;k<5;k++) h[4+k]+=nm[wid][4+k][c]*m2;
  }
  #pragma unroll
  for(int kk=0;kk<9;kk++){ g_h0[(size_t)n*576+kk*64+lane]=h[kk]; hl[wid][kk][lane]=h[kk]; }
  asm volatile("s_waitcnt lgkmcnt(0)" ::: "memory");
  float o[9];
  #pragma unroll
  for(int kk=0;kk<9;kk++) o[kk]=0.f;
  for(int c=0;c<64;c++){
    float r0=read[c*64+lane], r1=read[4096+c*64+lane], r2=read[8192+c*64+lane];
    o[0]+=hl[wid][0][c]*r0;
    #pragma unroll
    for(int k=0;k<3;k++) o[1+k]+=hl[wid][1+k][c]*r1;
    #pragma unroll
    for(int k=0;k<5;k++) o[4+k]+=hl[wid][4+k][c]*r2;
  }
  float* op=&out[(size_t)n*1152];
  op[lane]=o[0];
  #pragma unroll
  for(int k=0;k<3;k++) op[64 + lane*3+k]=o[1+k];
  #pragma unroll
  for(int k=0;k<5;k++) op[256 + lane*5+k]=o[4+k];
}

// ---------------- node update 1 (wave per node) ----------------
__global__ __launch_bounds__(256) void k_node1(const float* __restrict__ mix,
    const float* __restrict__ skip, const float* __restrict__ read, float* __restrict__ out){
  __shared__ float nm[4][9][64];
  __shared__ float h0l[4][9][64];
  __shared__ float hn[4][9][64];
  int lane=threadIdx.x&63, wid=threadIdx.x>>6;
  int n=blockIdx.x*4+wid;
  #pragma unroll
  for(int kk=0;kk<9;kk++){
    nm[wid][kk][lane]=g_acc1[(size_t)n*576+kk*64+lane]*(1.f/16.f);
    h0l[wid][kk][lane]=g_h0[(size_t)n*576+kk*64+lane];
  }
  asm volatile("s_waitcnt lgkmcnt(0)" ::: "memory");
  float h[9];
  #pragma unroll
  for(int kk=0;kk<9;kk++) h[kk]=0.f;
  for(int c=0;c<64;c++){
    float m0=mix[c*64+lane], m1=mix[4096+c*64+lane], m2=mix[8192+c*64+lane];
    float s0=skip[c*64+lane], s1=skip[4096+c*64+lane], s2=skip[8192+c*64+lane];
    h[0]+=nm[wid][0][c]*m0 + h0l[wid][0][c]*s0;
    #pragma unroll
    for(int k=0;k<3;k++) h[1+k]+=nm[wid][1+k][c]*m1 + h0l[wid][1+k][c]*s1;
    #pragma unroll
    for(int k=0;k<5;k++) h[4+k]+=nm[wid][4+k][c]*m2 + h0l[wid][4+k][c]*s2;
  }
  #pragma unroll
  for(int kk=0;kk<9;kk++) hn[wid][kk][lane]=h[kk];
  asm volatile("s_waitcnt lgkmcnt(0)" ::: "memory");
  float o[9];
  #pragma unroll
  for(int kk=0;kk<9;kk++) o[kk]=0.f;
  for(int c=0;c<64;c++){
    float r0=read[c*64+lane], r1=read[4096+c*64+lane], r2=read[8192+c*64+lane];
    o[0]+=hn[wid][0][c]*r0;
    #pragma unroll
    for(int k=0;k<3;k++) o[1+k]+=hn[wid][1+k][c]*r1;
    #pragma unroll
    for(int k=0;k<5;k++) o[4+k]+=hn[wid][4+k][c]*r2;
  }
  float* op=&out[(size_t)n*1152 + 576];
  op[lane]=o[0];
  #pragma unroll
  for(int k=0;k<3;k++) op[64 + lane*3+k]=o[1+k];
  #pragma unroll
  for(int k=0;k<5;k++) op[256 + lane*5+k]=o[4+k];
}

extern "C" void kernel_launch(void* const* d_in, const int* in_sizes, int n_in,
                              void* d_out, int out_size, void* d_ws, size_t ws_size,
                              hipStream_t stream) {
  (void)in_sizes; (void)n_in; (void)out_size; (void)d_ws; (void)ws_size;
  const float* pos  =(const float*)d_in[0];
  const int*   spec =(const int*)  d_in[1];
  const int*   snd  =(const int*)  d_in[2];
  const int*   rcv  =(const int*)  d_in[3];
  const float* wemb =(const float*)d_in[4];
  const float* w1_0 =(const float*)d_in[5];
  const float* w2_0 =(const float*)d_in[6];
  const float* mix0 =(const float*)d_in[7];
  const float* read0=(const float*)d_in[8];
  const float* w1_1 =(const float*)d_in[9];
  const float* w2_1 =(const float*)d_in[10];
  const float* mix1 =(const float*)d_in[11];
  const float* skip1=(const float*)d_in[12];
  const float* read1=(const float*)d_in[13];
  float* out=(float*)d_out;

  k_cg<<<1,1024,0,stream>>>();
  k_zero<<<(NN+255)/256,256,0,stream>>>();
  k_edge<<<(NE+255)/256,256,0,stream>>>(pos,snd,rcv);
  k_hist<<<NE/256,256,0,stream>>>(rcv);
  k_scan<<<1,1024,0,stream>>>();
  k_scatter<<<NE/256,256,0,stream>>>(rcv);
  k_hidden<<<NE*64/256,256,0,stream>>>(w1_0,w1_1);
  k_repack<192><<<6,256,0,stream>>>(w2_0);
  k_repack<832><<<26,256,0,stream>>>(w2_1);
  k_wgemm<192><<<NE/128,256,0,stream>>>();
  k_wgemm<832><<<NE/128,256,0,stream>>>();
  k_gather0<<<NN/4,256,0,stream>>>(snd,spec,wemb);
  k_node0<<<NN/4,256,0,stream>>>(mix0,read0,out);
  k_gather1<<<NN/4,256,0,stream>>>(snd);
  k_node1<<<NN/4,256,0,stream>>>(mix1,skip1,read1,out);
}